// Round 15
// baseline (119.703 us; speedup 1.0000x reference)
//
#include <hip/hip_runtime.h>
#include <hip/hip_fp16.h>
#include <cstdint>
#include <cstddef>

// ---- problem constants ----
#define SEQ 2048
#define DM 1024
#define NH 16
#define NB 20

typedef _Float16 half8 __attribute__((ext_vector_type(8)));
typedef _Float16 half4 __attribute__((ext_vector_type(4)));
typedef _Float16 h2v __attribute__((ext_vector_type(2)));
typedef float f32x4 __attribute__((ext_vector_type(4)));
typedef int i32x4 __attribute__((ext_vector_type(4)));
typedef unsigned int u32;
typedef unsigned int u32x2 __attribute__((ext_vector_type(2)));

// ws layout (25,165,824 B total):
//  KF [2][16][64][2048] halves : per (b,h,kt): [k2][dh][lane][8]       (QK^T A-frags, 16x16x32)
//  VF [2][16][64][2048] halves : per (b,h,kt): [dt][lane][k2*4+r]      (PV B-frags, K=32 pi-order)
//  PB [2][64][65536] bytes     : per (b,qblk32): [kt][lane][qs][k2][4] bucket*4|sentinel80
#define KF_HALVES 4194304
#define VF_HALVES 4194304

// =================== prepass (unchanged from R11) ===================
__global__ __launch_bounds__(256) void pa_prep(
    const float* __restrict__ v, const float* __restrict__ k,
    const int* __restrict__ diff, const int* __restrict__ mask,
    _Float16* __restrict__ KF, _Float16* __restrict__ VF,
    unsigned char* __restrict__ PB) {
  const int bid = blockIdx.x, tid = threadIdx.x;
  if (bid < 2048) {
    int img = bid >> 4;                    // 0..127 = b*64+kt
    int bb = img >> 6, kt = img & 63;
    int tix = ((bid & 15) << 8) | tid;     // 0..4095
    int r = tix >> 7;                      // row in tile 0..31 (= k2*16+l16)
    int c0 = (tix & 127) << 3;             // col 0..1016
    const float* src = k + ((size_t)(bb * SEQ + kt * 32 + r)) * DM + c0;
    f32x4 a = *(const f32x4*)src;
    f32x4 c = *(const f32x4*)(src + 4);
    half8 o = {(_Float16)a[0], (_Float16)a[1], (_Float16)a[2], (_Float16)a[3],
               (_Float16)c[0], (_Float16)c[1], (_Float16)c[2], (_Float16)c[3]};
    int h = c0 >> 6, dh = (c0 >> 5) & 1, g4 = (c0 >> 3) & 3;
    int k2 = r >> 4, l16 = r & 15;
    int lane = g4 * 16 + l16;
    size_t off = ((size_t)((bb * 16 + h) * 64 + kt)) * 2048 + (k2 * 2 + dh) * 512 + lane * 8;
    *(half8*)(KF + off) = o;
  } else if (bid < 3072) {
    int b3 = bid - 2048;
    int img = b3 >> 3;                     // 0..127
    int bb = img >> 6, kt = img & 63;
    int tix = ((b3 & 7) << 8) | tid;       // 0..2047
    int kq = tix >> 8;                     // 0..7
    int k2 = kq >> 2, g4 = kq & 3;
    int d0 = (tix & 255) << 2;             // 0..1020
    const float* src = v + ((size_t)(bb * SEQ + kt * 32 + k2 * 16 + g4 * 4)) * DM + d0;
    f32x4 m0 = *(const f32x4*)(src);
    f32x4 m1 = *(const f32x4*)(src + DM);
    f32x4 m2 = *(const f32x4*)(src + 2 * DM);
    f32x4 m3 = *(const f32x4*)(src + 3 * DM);
#pragma unroll
    for (int i = 0; i < 4; ++i) {
      int d = d0 + i;
      int l16 = d & 15, dt = (d >> 4) & 3, h = d >> 6;
      int lane = g4 * 16 + l16;
      half4 o = {(_Float16)m0[i], (_Float16)m1[i], (_Float16)m2[i], (_Float16)m3[i]};
      size_t off = ((size_t)((bb * 16 + h) * 64 + kt)) * 2048 + dt * 512 + lane * 8 + k2 * 4;
      *(half4*)(VF + off) = o;
    }
  } else {
    int b4 = bid - 3072;                   // 0..4095
    int job = b4 >> 5;                     // 0..127 = b*64+qblk32
    int bb = job >> 6, qblk = job & 63;
    int tix = ((b4 & 31) << 8) | tid;      // 0..8191
    int kt = tix >> 7;
    int rem = tix & 127;
    int g4 = rem & 3, l16 = (rem >> 2) & 15, qs = rem >> 6;
    int lane = g4 * 16 + l16;
    int qrow = qblk * 32 + qs * 16 + l16;
    size_t rowbase = ((size_t)(bb * SEQ + qrow)) * SEQ;
    u32x2 wds;
#pragma unroll
    for (int k2 = 0; k2 < 2; ++k2) {
      int kk = kt * 32 + k2 * 16 + g4 * 4;
      i32x4 dv = *(const i32x4*)(diff + rowbase + kk);
      i32x4 mv = *(const i32x4*)(mask + rowbase + kk);
      u32 wd = 0;
#pragma unroll
      for (int r = 0; r < 4; ++r) {
        u32 byte = mv[r] ? ((u32)dv[r] << 2) : 80u;  // bucket*4; 80 = masked sentinel lane 20
        wd |= byte << (8 * r);
      }
      wds[k2] = wd;
    }
    size_t off = ((size_t)job) * 65536 + (size_t)kt * 1024 + (size_t)lane * 16 + (size_t)qs * 8;
    *(u32x2*)(PB + off) = wds;
  }
}

__device__ __forceinline__ void gll16(const _Float16* g, _Float16* l) {
  __builtin_amdgcn_global_load_lds(
      (const __attribute__((address_space(1))) unsigned int*)g,
      (__attribute__((address_space(3))) unsigned int*)l, 16, 0, 0);
}

// packed-f16 silu with f16 bias pairs; masked bias=-3e4 -> y = -0 exactly
__device__ __forceinline__ half4 silu4b(const f32x4& s, h2v b01, h2v b23) {
  h2v x01 = __builtin_bit_cast(h2v, __builtin_amdgcn_cvt_pkrtz(s[0], s[1])) + b01;
  h2v x23 = __builtin_bit_cast(h2v, __builtin_amdgcn_cvt_pkrtz(s[2], s[3])) + b23;
  const h2v NL2E = {(_Float16)-1.44269504f, (_Float16)-1.44269504f};
  const h2v ONE = {(_Float16)1.0f, (_Float16)1.0f};
  h2v m01 = x01 * NL2E, m23 = x23 * NL2E;
  h2v e01 = __builtin_bit_cast(h2v, h2exp2(__builtin_bit_cast(__half2, m01)));
  h2v e23 = __builtin_bit_cast(h2v, h2exp2(__builtin_bit_cast(__half2, m23)));
  h2v d01 = e01 + ONE, d23 = e23 + ONE;
  h2v y01 = x01 * __builtin_bit_cast(h2v, h2rcp(__builtin_bit_cast(__half2, d01)));
  h2v y23 = x23 * __builtin_bit_cast(h2v, h2rcp(__builtin_bit_cast(__half2, d23)));
  return (half4){y01[0], y01[1], y23[0], y23[1]};
}

// =================== main: counted-vmcnt LDS ring (T3/T4 pattern) ===================
// R14 proved time is invariant to waves & per-wave batching -> each wave pays an exposed
// memory round-trip per tile; every HIP-level prefetch collapsed (compiler waitcnt).
// Fix: ALL in-loop VMEM is global_load_lds into a 4-slot block ring (K|V|PB = 12KB/slot,
// 48KB tot); raw s_barrier + inline-asm s_waitcnt vmcnt(6) keeps slots t+1,t+2 in flight
// while computing t. No compiler-tracked loads remain in the loop.
__global__ __launch_bounds__(256) void pa_main(
    const _Float16* __restrict__ KF, const _Float16* __restrict__ VF,
    const unsigned char* __restrict__ PB, const float* __restrict__ q,
    const float* __restrict__ relbias, float* __restrict__ out) {
  __shared__ __align__(16) unsigned char ring[4][12288];  // [slot]: K 4KB | V 4KB | PB 4KB

  const int tid = threadIdx.x, lane = tid & 63, wid = tid >> 6;
  const int l16 = lane & 15, g4 = lane >> 4;
  const int L = (blockIdx.x & 7) * 128 + (blockIdx.x >> 3);   // bijective, 8 XCDs x 128
  const int h = L & 15;
  const int qgrp = (L >> 4) & 15;
  const int ksp = (L >> 8) & 1;
  const int b = L >> 9;
  const int qblk = qgrp * 4 + wid;
  const int qbase = qblk * 32;

  const float rbv = (lane < NB) ? relbias[lane * NH + h] : -30000.0f;
  const int rbi = __float_as_int(rbv);

  half8 qf[2][2];
#pragma unroll
  for (int qs = 0; qs < 2; ++qs)
#pragma unroll
    for (int dh = 0; dh < 2; ++dh) {
      const float* s = q + ((size_t)(b * SEQ + qbase + qs * 16 + l16)) * DM + h * 64 + dh * 32 + g4 * 8;
      f32x4 a = *(const f32x4*)s;
      f32x4 c = *(const f32x4*)(s + 4);
      qf[qs][dh] = {(_Float16)(a[0] * 0.125f), (_Float16)(a[1] * 0.125f),
                    (_Float16)(a[2] * 0.125f), (_Float16)(a[3] * 0.125f),
                    (_Float16)(c[0] * 0.125f), (_Float16)(c[1] * 0.125f),
                    (_Float16)(c[2] * 0.125f), (_Float16)(c[3] * 0.125f)};
    }

  f32x4 acc[2][4];
#pragma unroll
  for (int qs = 0; qs < 2; ++qs)
#pragma unroll
    for (int dt = 0; dt < 4; ++dt) acc[qs][dt] = (f32x4){0.f, 0.f, 0.f, 0.f};

  // global sources (fragment-linear). Wave w stages chunk w of K and V + its own PB slice.
  const _Float16* kfb = KF + ((size_t)((b * 16 + h) * 64 + ksp * 32)) * 2048 + wid * 512 + lane * 8;
  const _Float16* vfb = VF + ((size_t)((b * 16 + h) * 64 + ksp * 32)) * 2048 + wid * 512 + lane * 8;
  const unsigned char* pbb = PB + ((size_t)(b * 64 + qblk)) * 65536 + (size_t)(ksp * 32) * 1024 + lane * 16;

#define STAGE(T)                                                              \
  do {                                                                        \
    int sl_ = (T) & 3;                                                        \
    gll16(kfb + (size_t)(T) * 2048, (_Float16*)(ring[sl_] + wid * 1024));     \
    gll16(vfb + (size_t)(T) * 2048, (_Float16*)(ring[sl_] + 4096 + wid * 1024)); \
    gll16((const _Float16*)(pbb + (size_t)(T) * 1024),                        \
          (_Float16*)(ring[sl_] + 8192 + wid * 1024));                        \
  } while (0)

#define COMPUTE(T)                                                                           \
  do {                                                                                       \
    int sl_ = (T) & 3;                                                                       \
    const _Float16* Ks_ = (const _Float16*)(ring[sl_]);                                      \
    const _Float16* Vs_ = (const _Float16*)(ring[sl_] + 4096);                               \
    i32x4 pq = *(const i32x4*)(ring[sl_] + 8192 + wid * 1024 + lane * 16);                   \
    h2v bias[2][2][2];                                                                       \
    _Pragma("unroll") for (int qs = 0; qs < 2; ++qs)                                         \
      _Pragma("unroll") for (int k2 = 0; k2 < 2; ++k2) {                                     \
        u32 u = (u32)pq[qs * 2 + k2];                                                        \
        float b0 = __int_as_float(__builtin_amdgcn_ds_bpermute((int)(u & 0xffu), rbi));      \
        float b1 = __int_as_float(__builtin_amdgcn_ds_bpermute((int)((u >> 8) & 0xffu), rbi)); \
        float b2 = __int_as_float(__builtin_amdgcn_ds_bpermute((int)((u >> 16) & 0xffu), rbi)); \
        float b3 = __int_as_float(__builtin_amdgcn_ds_bpermute((int)(u >> 24), rbi));        \
        bias[qs][k2][0] = __builtin_bit_cast(h2v, __builtin_amdgcn_cvt_pkrtz(b0, b1));       \
        bias[qs][k2][1] = __builtin_bit_cast(h2v, __builtin_amdgcn_cvt_pkrtz(b2, b3));       \
      }                                                                                      \
    half8 kfr[4], vvr[4];                                                                    \
    _Pragma("unroll") for (int j = 0; j < 4; ++j) {                                          \
      kfr[j] = *(const half8*)&Ks_[j * 512 + lane * 8];                                      \
      vvr[j] = *(const half8*)&Vs_[j * 512 + lane * 8];                                      \
    }                                                                                        \
    const f32x4 zf = {0.f, 0.f, 0.f, 0.f};                                                   \
    _Pragma("unroll") for (int qs = 0; qs < 2; ++qs) {                                       \
      f32x4 sa0 = __builtin_amdgcn_mfma_f32_16x16x32_f16(kfr[0], qf[qs][0], zf, 0, 0, 0);    \
      sa0 = __builtin_amdgcn_mfma_f32_16x16x32_f16(kfr[1], qf[qs][1], sa0, 0, 0, 0);         \
      f32x4 sa1 = __builtin_amdgcn_mfma_f32_16x16x32_f16(kfr[2], qf[qs][0], zf, 0, 0, 0);    \
      sa1 = __builtin_amdgcn_mfma_f32_16x16x32_f16(kfr[3], qf[qs][1], sa1, 0, 0, 0);         \
      half4 p0 = silu4b(sa0, bias[qs][0][0], bias[qs][0][1]);                                \
      half4 p1 = silu4b(sa1, bias[qs][1][0], bias[qs][1][1]);                                \
      half8 pf8 = (half8){p0[0], p0[1], p0[2], p0[3], p1[0], p1[1], p1[2], p1[3]};           \
      _Pragma("unroll") for (int dt = 0; dt < 4; ++dt)                                       \
        acc[qs][dt] = __builtin_amdgcn_mfma_f32_16x16x32_f16(pf8, vvr[dt], acc[qs][dt], 0, 0, 0); \
    }                                                                                        \
  } while (0)

  // prologue: stage slots 0,1,2 (9 gll16 in flight)
  STAGE(0);
  STAGE(1);
  STAGE(2);
  __builtin_amdgcn_sched_barrier(0);

  for (int t = 0; t < 31; ++t) {
    // allow slots t+1,t+2 (6 ops) in flight; force slot t complete
    asm volatile("s_waitcnt vmcnt(6)" ::: "memory");
    __builtin_amdgcn_sched_barrier(0);
    __builtin_amdgcn_s_barrier();           // raw barrier: no vmcnt(0) drain
    if (t + 3 < 32) STAGE(t + 3);           // overwrites slot (t+3)&3 = slot of t-1 (all done)
    __builtin_amdgcn_sched_barrier(0);
    COMPUTE(t);
  }
  asm volatile("s_waitcnt vmcnt(0)" ::: "memory");
  __builtin_amdgcn_sched_barrier(0);
  __builtin_amdgcn_s_barrier();
  COMPUTE(31);
#undef STAGE
#undef COMPUTE

  // epilogue: ksplit=2 partials -> atomicAdd into zeroed out
#pragma unroll
  for (int qs = 0; qs < 2; ++qs)
#pragma unroll
    for (int dt = 0; dt < 4; ++dt)
#pragma unroll
      for (int r = 0; r < 4; ++r) {
        int qrow = qbase + qs * 16 + g4 * 4 + r;
        int d = h * 64 + dt * 16 + l16;
        atomicAdd(&out[((size_t)(b * SEQ) + qrow) * DM + d], acc[qs][dt][r]);
      }
}

extern "C" void kernel_launch(void* const* d_in, const int* in_sizes, int n_in,
                              void* d_out, int out_size, void* d_ws, size_t ws_size,
                              hipStream_t stream) {
  const float* v = (const float*)d_in[0];
  const float* k = (const float*)d_in[1];
  const float* q = (const float*)d_in[2];
  const int* mask = (const int*)d_in[3];
  const int* diff = (const int*)d_in[4];
  const float* relbias = (const float*)d_in[5];
  float* out = (float*)d_out;

  _Float16* KF = (_Float16*)d_ws;
  _Float16* VF = KF + KF_HALVES;
  unsigned char* PB = (unsigned char*)(VF + VF_HALVES);
  if (ws_size < (size_t)25165824) return;

  (void)hipMemsetAsync(d_out, 0, (size_t)out_size * sizeof(float), stream);
  pa_prep<<<7168, 256, 0, stream>>>(v, k, diff, mask, KF, VF, PB);
  pa_main<<<1024, 256, 0, stream>>>(KF, VF, PB, q, relbias, out);
}

// Round 16
// 98.968 us; speedup vs baseline: 1.2095x; 1.2095x over previous
//
#include <hip/hip_runtime.h>
#include <hip/hip_fp16.h>
#include <cstdint>
#include <cstddef>

// ---- problem constants ----
#define SEQ 2048
#define DM 1024
#define NH 16
#define NB 20

typedef _Float16 half8 __attribute__((ext_vector_type(8)));
typedef _Float16 half4 __attribute__((ext_vector_type(4)));
typedef _Float16 h2v __attribute__((ext_vector_type(2)));
typedef float f32x4 __attribute__((ext_vector_type(4)));
typedef int i32x4 __attribute__((ext_vector_type(4)));
typedef unsigned int u32;
typedef unsigned int u32x2 __attribute__((ext_vector_type(2)));

// ws layout (25,165,824 B total):
//  KF [2][16][64][2048] halves : per (b,h,kt): [k2][dh][lane][8]       (QK^T A-frags, 16x16x32)
//  VF [2][16][64][2048] halves : per (b,h,kt): [dt][lane][k2*4+r]      (PV B-frags, K=32 pi-order)
//  PB [2][64][65536] bytes     : per (b,qblk32): [kt][lane][qs][k2][4] bucket*4|sentinel80
#define KF_HALVES 4194304
#define VF_HALVES 4194304

// =================== prepass (unchanged) ===================
__global__ __launch_bounds__(256) void pa_prep(
    const float* __restrict__ v, const float* __restrict__ k,
    const int* __restrict__ diff, const int* __restrict__ mask,
    _Float16* __restrict__ KF, _Float16* __restrict__ VF,
    unsigned char* __restrict__ PB) {
  const int bid = blockIdx.x, tid = threadIdx.x;
  if (bid < 2048) {
    int img = bid >> 4;                    // 0..127 = b*64+kt
    int bb = img >> 6, kt = img & 63;
    int tix = ((bid & 15) << 8) | tid;     // 0..4095
    int r = tix >> 7;                      // row in tile 0..31 (= k2*16+l16)
    int c0 = (tix & 127) << 3;             // col 0..1016
    const float* src = k + ((size_t)(bb * SEQ + kt * 32 + r)) * DM + c0;
    f32x4 a = *(const f32x4*)src;
    f32x4 c = *(const f32x4*)(src + 4);
    half8 o = {(_Float16)a[0], (_Float16)a[1], (_Float16)a[2], (_Float16)a[3],
               (_Float16)c[0], (_Float16)c[1], (_Float16)c[2], (_Float16)c[3]};
    int h = c0 >> 6, dh = (c0 >> 5) & 1, g4 = (c0 >> 3) & 3;
    int k2 = r >> 4, l16 = r & 15;
    int lane = g4 * 16 + l16;
    size_t off = ((size_t)((bb * 16 + h) * 64 + kt)) * 2048 + (k2 * 2 + dh) * 512 + lane * 8;
    *(half8*)(KF + off) = o;
  } else if (bid < 3072) {
    int b3 = bid - 2048;
    int img = b3 >> 3;                     // 0..127
    int bb = img >> 6, kt = img & 63;
    int tix = ((b3 & 7) << 8) | tid;       // 0..2047
    int kq = tix >> 8;                     // 0..7
    int k2 = kq >> 2, g4 = kq & 3;
    int d0 = (tix & 255) << 2;             // 0..1020
    const float* src = v + ((size_t)(bb * SEQ + kt * 32 + k2 * 16 + g4 * 4)) * DM + d0;
    f32x4 m0 = *(const f32x4*)(src);
    f32x4 m1 = *(const f32x4*)(src + DM);
    f32x4 m2 = *(const f32x4*)(src + 2 * DM);
    f32x4 m3 = *(const f32x4*)(src + 3 * DM);
#pragma unroll
    for (int i = 0; i < 4; ++i) {
      int d = d0 + i;
      int l16 = d & 15, dt = (d >> 4) & 3, h = d >> 6;
      int lane = g4 * 16 + l16;
      half4 o = {(_Float16)m0[i], (_Float16)m1[i], (_Float16)m2[i], (_Float16)m3[i]};
      size_t off = ((size_t)((bb * 16 + h) * 64 + kt)) * 2048 + dt * 512 + lane * 8 + k2 * 4;
      *(half4*)(VF + off) = o;
    }
  } else {
    int b4 = bid - 3072;                   // 0..4095
    int job = b4 >> 5;                     // 0..127 = b*64+qblk32
    int bb = job >> 6, qblk = job & 63;
    int tix = ((b4 & 31) << 8) | tid;      // 0..8191
    int kt = tix >> 7;
    int rem = tix & 127;
    int g4 = rem & 3, l16 = (rem >> 2) & 15, qs = rem >> 6;
    int lane = g4 * 16 + l16;
    int qrow = qblk * 32 + qs * 16 + l16;
    size_t rowbase = ((size_t)(bb * SEQ + qrow)) * SEQ;
    u32x2 wds;
#pragma unroll
    for (int k2 = 0; k2 < 2; ++k2) {
      int kk = kt * 32 + k2 * 16 + g4 * 4;
      i32x4 dv = *(const i32x4*)(diff + rowbase + kk);
      i32x4 mv = *(const i32x4*)(mask + rowbase + kk);
      u32 wd = 0;
#pragma unroll
      for (int r = 0; r < 4; ++r) {
        u32 byte = mv[r] ? ((u32)dv[r] << 2) : 80u;  // bucket*4; 80 = masked sentinel lane 20
        wd |= byte << (8 * r);
      }
      wds[k2] = wd;
    }
    size_t off = ((size_t)job) * 65536 + (size_t)kt * 1024 + (size_t)lane * 16 + (size_t)qs * 8;
    *(u32x2*)(PB + off) = wds;
  }
}

__device__ __forceinline__ void gll16(const _Float16* g, _Float16* l) {
  __builtin_amdgcn_global_load_lds(
      (const __attribute__((address_space(1))) unsigned int*)g,
      (__attribute__((address_space(3))) unsigned int*)l, 16, 0, 0);
}

// packed-f16 silu; bias already in s (came through the MFMA C-operand in f32)
__device__ __forceinline__ half4 silu4nb(const f32x4& s) {
  h2v x01 = __builtin_bit_cast(h2v, __builtin_amdgcn_cvt_pkrtz(s[0], s[1]));
  h2v x23 = __builtin_bit_cast(h2v, __builtin_amdgcn_cvt_pkrtz(s[2], s[3]));
  const h2v NL2E = {(_Float16)-1.44269504f, (_Float16)-1.44269504f};
  const h2v ONE = {(_Float16)1.0f, (_Float16)1.0f};
  h2v m01 = x01 * NL2E, m23 = x23 * NL2E;
  h2v e01 = __builtin_bit_cast(h2v, h2exp2(__builtin_bit_cast(__half2, m01)));
  h2v e23 = __builtin_bit_cast(h2v, h2exp2(__builtin_bit_cast(__half2, m23)));
  h2v d01 = e01 + ONE, d23 = e23 + ONE;
  h2v y01 = x01 * __builtin_bit_cast(h2v, h2rcp(__builtin_bit_cast(__half2, d01)));
  h2v y23 = x23 * __builtin_bit_cast(h2v, h2rcp(__builtin_bit_cast(__half2, d23)));
  return (half4){y01[0], y01[1], y23[0], y23[1]};
}

struct BiasSet { f32x4 b[2][2]; };  // [qs][k2], f32 — feeds QK C-operand

__device__ __forceinline__ void gather_bias(BiasSet& bs, const i32x4& pq, int rbi) {
#pragma unroll
  for (int qs = 0; qs < 2; ++qs)
#pragma unroll
    for (int k2 = 0; k2 < 2; ++k2) {
      u32 u = (u32)pq[qs * 2 + k2];
      bs.b[qs][k2][0] = __int_as_float(__builtin_amdgcn_ds_bpermute((int)(u & 0xffu), rbi));
      bs.b[qs][k2][1] = __int_as_float(__builtin_amdgcn_ds_bpermute((int)((u >> 8) & 0xffu), rbi));
      bs.b[qs][k2][2] = __int_as_float(__builtin_amdgcn_ds_bpermute((int)((u >> 16) & 0xffu), rbi));
      bs.b[qs][k2][3] = __int_as_float(__builtin_amdgcn_ds_bpermute((int)(u >> 24), rbi));
    }
}

// =================== main: R11 body, full-k per wave (overhead cut) ===================
// 11 structures -> 80-92us plateau (all pipes <50%); R14: time invariant to per-wave
// batching. So keep best body (R11, 80.5us) and cut the ~29us NON-main overhead:
// full k-range per wave (64 tiles) -> ksplit=1 -> NO memset dispatch, NO atomicAdd RMW
// (plain stores, WRITE 33->16MB). 512 blocks; XCD owns (b, 4 heads): 2MB K/V in its L2.
__global__ __launch_bounds__(256, 4) void pa_main(
    const _Float16* __restrict__ KF, const _Float16* __restrict__ VF,
    const unsigned char* __restrict__ PB, const float* __restrict__ q,
    const float* __restrict__ relbias, float* __restrict__ out) {
  __shared__ _Float16 ldsK[2][2048];
  __shared__ _Float16 ldsV[2][2048];

  const int tid = threadIdx.x, lane = tid & 63, wid = tid >> 6;
  const int l16 = lane & 15, g4 = lane >> 4;
  const int xcd = blockIdx.x & 7;        // bid%8 = XCD
  const int i = blockIdx.x >> 3;         // 0..63 within XCD
  const int b = xcd >> 2;                // XCD owns (b, 4-head group)
  const int hg = xcd & 3;
  const int h = hg * 4 + (i & 3);
  const int qgrp = i >> 2;               // 0..15
  const int qblk = qgrp * 4 + wid;
  const int qbase = qblk * 32;

  const float rbv = (lane < NB) ? relbias[lane * NH + h] : -30000.0f;
  const int rbi = __float_as_int(rbv);

  half8 qf[2][2];
#pragma unroll
  for (int qs = 0; qs < 2; ++qs)
#pragma unroll
    for (int dh = 0; dh < 2; ++dh) {
      const float* s = q + ((size_t)(b * SEQ + qbase + qs * 16 + l16)) * DM + h * 64 + dh * 32 + g4 * 8;
      f32x4 a = *(const f32x4*)s;
      f32x4 c = *(const f32x4*)(s + 4);
      qf[qs][dh] = {(_Float16)(a[0] * 0.125f), (_Float16)(a[1] * 0.125f),
                    (_Float16)(a[2] * 0.125f), (_Float16)(a[3] * 0.125f),
                    (_Float16)(c[0] * 0.125f), (_Float16)(c[1] * 0.125f),
                    (_Float16)(c[2] * 0.125f), (_Float16)(c[3] * 0.125f)};
    }

  f32x4 acc[2][4];
#pragma unroll
  for (int qs = 0; qs < 2; ++qs)
#pragma unroll
    for (int dt = 0; dt < 4; ++dt) acc[qs][dt] = (f32x4){0.f, 0.f, 0.f, 0.f};

  const _Float16* kfb = KF + ((size_t)((b * 16 + h) * 64)) * 2048 + lane * 8;
  const _Float16* vfb = VF + ((size_t)((b * 16 + h) * 64)) * 2048 + lane * 8;
  const unsigned char* pbb = PB + ((size_t)(b * 64 + qblk)) * 65536 + lane * 16;
  const int c512 = wid * 512;

#define STAGE(T, B)                                          \
  do {                                                       \
    gll16(kfb + (size_t)(T) * 2048 + c512, &ldsK[B][c512]);  \
    gll16(vfb + (size_t)(T) * 2048 + c512, &ldsV[B][c512]);  \
  } while (0)
#define CLMP(T) ((T) < 64 ? (T) : 63)

#define COMPUTE(B, BS)                                                                       \
  do {                                                                                       \
    half8 kfr[4], vvr[4];                                                                    \
    _Pragma("unroll") for (int j = 0; j < 4; ++j) {                                          \
      kfr[j] = *(const half8*)&ldsK[B][j * 512 + lane * 8];                                  \
      vvr[j] = *(const half8*)&ldsV[B][j * 512 + lane * 8];                                  \
    }                                                                                        \
    f32x4 sa[2][2];                                                                          \
    _Pragma("unroll") for (int qs = 0; qs < 2; ++qs)                                         \
      _Pragma("unroll") for (int k2 = 0; k2 < 2; ++k2) {                                     \
        sa[qs][k2] = __builtin_amdgcn_mfma_f32_16x16x32_f16(kfr[k2 * 2 + 0], qf[qs][0],      \
                                                            BS.b[qs][k2], 0, 0, 0);          \
        sa[qs][k2] = __builtin_amdgcn_mfma_f32_16x16x32_f16(kfr[k2 * 2 + 1], qf[qs][1],      \
                                                            sa[qs][k2], 0, 0, 0);            \
      }                                                                                      \
    half8 pf8[2];                                                                            \
    _Pragma("unroll") for (int qs = 0; qs < 2; ++qs) {                                       \
      half4 p0 = silu4nb(sa[qs][0]);                                                         \
      half4 p1 = silu4nb(sa[qs][1]);                                                         \
      pf8[qs] = (half8){p0[0], p0[1], p0[2], p0[3], p1[0], p1[1], p1[2], p1[3]};             \
    }                                                                                        \
    _Pragma("unroll") for (int qs = 0; qs < 2; ++qs)                                         \
      _Pragma("unroll") for (int dt = 0; dt < 4; ++dt)                                       \
        acc[qs][dt] = __builtin_amdgcn_mfma_f32_16x16x32_f16(pf8[qs], vvr[dt],               \
                                                             acc[qs][dt], 0, 0, 0);          \
  } while (0)

  BiasSet biasA, biasB;
  i32x4 pq1, pqX;

  // prologue: stage tile0 -> buf0; bias(0); pq(1) in flight
  STAGE(0, 0);
  i32x4 pq0 = *(const i32x4*)(pbb);
  pq1 = *(const i32x4*)(pbb + 1024);
  __syncthreads();                      // drains stage(0)
  gather_bias(biasA, pq0, rbi);

  for (int t = 0; t < 64; t += 2) {
    // even phase: stage t+1 -> buf1; compute t from buf0
    STAGE(t + 1, 1);
    pqX = *(const i32x4*)(pbb + (size_t)CLMP(t + 2) * 1024);
    __builtin_amdgcn_sched_barrier(0);
    gather_bias(biasB, pq1, rbi);       // bias for t+1, hides under compute t
    COMPUTE(0, biasA);
    __syncthreads();                    // buf1 ready; all waves done with buf0
    // odd phase: stage t+2 -> buf0; compute t+1 from buf1
    STAGE(CLMP(t + 2), 0);
    pq1 = *(const i32x4*)(pbb + (size_t)CLMP(t + 3) * 1024);
    __builtin_amdgcn_sched_barrier(0);
    gather_bias(biasA, pqX, rbi);       // bias for t+2
    COMPUTE(1, biasB);
    __syncthreads();
  }
#undef STAGE
#undef CLMP
#undef COMPUTE

  // epilogue: full-k accumulators -> direct stores (no memset, no atomics)
#pragma unroll
  for (int qs = 0; qs < 2; ++qs)
#pragma unroll
    for (int dt = 0; dt < 4; ++dt)
#pragma unroll
      for (int r = 0; r < 4; ++r) {
        int qrow = qbase + qs * 16 + g4 * 4 + r;
        int d = h * 64 + dt * 16 + l16;
        out[((size_t)(b * SEQ) + qrow) * DM + d] = acc[qs][dt][r];
      }
}

extern "C" void kernel_launch(void* const* d_in, const int* in_sizes, int n_in,
                              void* d_out, int out_size, void* d_ws, size_t ws_size,
                              hipStream_t stream) {
  const float* v = (const float*)d_in[0];
  const float* k = (const float*)d_in[1];
  const float* q = (const float*)d_in[2];
  const int* mask = (const int*)d_in[3];
  const int* diff = (const int*)d_in[4];
  const float* relbias = (const float*)d_in[5];
  float* out = (float*)d_out;

  _Float16* KF = (_Float16*)d_ws;
  _Float16* VF = KF + KF_HALVES;
  unsigned char* PB = (unsigned char*)(VF + VF_HALVES);
  if (ws_size < (size_t)25165824) return;

  pa_prep<<<7168, 256, 0, stream>>>(v, k, diff, mask, KF, VF, PB);
  pa_main<<<512, 256, 0, stream>>>(KF, VF, PB, q, relbias, out);
}

// Round 17
// 91.440 us; speedup vs baseline: 1.3091x; 1.0823x over previous
//
#include <hip/hip_runtime.h>
#include <hip/hip_fp16.h>
#include <cstdint>
#include <cstddef>

// ---- problem constants ----
#define SEQ 2048
#define DM 1024
#define NH 16
#define NB 20

typedef _Float16 half8 __attribute__((ext_vector_type(8)));
typedef _Float16 half4 __attribute__((ext_vector_type(4)));
typedef _Float16 h2v __attribute__((ext_vector_type(2)));
typedef float f32x4 __attribute__((ext_vector_type(4)));
typedef float f32x2 __attribute__((ext_vector_type(2)));
typedef int i32x4 __attribute__((ext_vector_type(4)));
typedef unsigned int u32;
typedef unsigned int u32x2 __attribute__((ext_vector_type(2)));

// ws layout (25,165,824 B total):
//  KF [2][16][64][2048] halves : per (b,h,kt): [k2][dh][lane][8]       (QK^T A-frags, 16x16x32)
//  VF [2][16][64][2048] halves : per (b,h,kt): [dt][lane][k2*4+r]      (PV B-frags, K=32 pi-order)
//  PB [2][64][65536] bytes     : per (b,qblk32): [kt][lane][qs][k2] u32 = pair01 | pair23<<16
//                                pair = bucket0*21+bucket1 (bucket 20 = masked sentinel)
#define KF_HALVES 4194304
#define VF_HALVES 4194304

// =================== prepass ===================
__global__ __launch_bounds__(256) void pa_prep(
    const float* __restrict__ v, const float* __restrict__ k,
    const int* __restrict__ diff, const int* __restrict__ mask,
    _Float16* __restrict__ KF, _Float16* __restrict__ VF,
    unsigned char* __restrict__ PB) {
  const int bid = blockIdx.x, tid = threadIdx.x;
  if (bid < 2048) {
    int img = bid >> 4;                    // 0..127 = b*64+kt
    int bb = img >> 6, kt = img & 63;
    int tix = ((bid & 15) << 8) | tid;     // 0..4095
    int r = tix >> 7;                      // row in tile 0..31 (= k2*16+l16)
    int c0 = (tix & 127) << 3;             // col 0..1016
    const float* src = k + ((size_t)(bb * SEQ + kt * 32 + r)) * DM + c0;
    f32x4 a = *(const f32x4*)src;
    f32x4 c = *(const f32x4*)(src + 4);
    half8 o = {(_Float16)a[0], (_Float16)a[1], (_Float16)a[2], (_Float16)a[3],
               (_Float16)c[0], (_Float16)c[1], (_Float16)c[2], (_Float16)c[3]};
    int h = c0 >> 6, dh = (c0 >> 5) & 1, g4 = (c0 >> 3) & 3;
    int k2 = r >> 4, l16 = r & 15;
    int lane = g4 * 16 + l16;
    size_t off = ((size_t)((bb * 16 + h) * 64 + kt)) * 2048 + (k2 * 2 + dh) * 512 + lane * 8;
    *(half8*)(KF + off) = o;
  } else if (bid < 3072) {
    int b3 = bid - 2048;
    int img = b3 >> 3;                     // 0..127
    int bb = img >> 6, kt = img & 63;
    int tix = ((b3 & 7) << 8) | tid;       // 0..2047
    int kq = tix >> 8;                     // 0..7
    int k2 = kq >> 2, g4 = kq & 3;
    int d0 = (tix & 255) << 2;             // 0..1020
    const float* src = v + ((size_t)(bb * SEQ + kt * 32 + k2 * 16 + g4 * 4)) * DM + d0;
    f32x4 m0 = *(const f32x4*)(src);
    f32x4 m1 = *(const f32x4*)(src + DM);
    f32x4 m2 = *(const f32x4*)(src + 2 * DM);
    f32x4 m3 = *(const f32x4*)(src + 3 * DM);
#pragma unroll
    for (int i = 0; i < 4; ++i) {
      int d = d0 + i;
      int l16 = d & 15, dt = (d >> 4) & 3, h = d >> 6;
      int lane = g4 * 16 + l16;
      half4 o = {(_Float16)m0[i], (_Float16)m1[i], (_Float16)m2[i], (_Float16)m3[i]};
      size_t off = ((size_t)((bb * 16 + h) * 64 + kt)) * 2048 + dt * 512 + lane * 8 + k2 * 4;
      *(half4*)(VF + off) = o;
    }
  } else {
    int b4 = bid - 3072;                   // 0..4095
    int job = b4 >> 5;                     // 0..127 = b*64+qblk32
    int bb = job >> 6, qblk = job & 63;
    int tix = ((b4 & 31) << 8) | tid;      // 0..8191
    int kt = tix >> 7;
    int rem = tix & 127;
    int g4 = rem & 3, l16 = (rem >> 2) & 15, qs = rem >> 6;
    int lane = g4 * 16 + l16;
    int qrow = qblk * 32 + qs * 16 + l16;
    size_t rowbase = ((size_t)(bb * SEQ + qrow)) * SEQ;
    u32x2 wds;
#pragma unroll
    for (int k2 = 0; k2 < 2; ++k2) {
      int kk = kt * 32 + k2 * 16 + g4 * 4;
      i32x4 dv = *(const i32x4*)(diff + rowbase + kk);
      i32x4 mv = *(const i32x4*)(mask + rowbase + kk);
      u32 bk[4];
#pragma unroll
      for (int r = 0; r < 4; ++r) bk[r] = mv[r] ? (u32)dv[r] : 20u;  // 20 = masked sentinel
      u32 pi01 = bk[0] * 21 + bk[1];
      u32 pi23 = bk[2] * 21 + bk[3];
      wds[k2] = pi01 | (pi23 << 16);
    }
    size_t off = ((size_t)job) * 65536 + (size_t)kt * 1024 + (size_t)lane * 16 + (size_t)qs * 8;
    *(u32x2*)(PB + off) = wds;
  }
}

__device__ __forceinline__ void gll16(const _Float16* g, _Float16* l) {
  __builtin_amdgcn_global_load_lds(
      (const __attribute__((address_space(1))) unsigned int*)g,
      (__attribute__((address_space(3))) unsigned int*)l, 16, 0, 0);
}

// packed-f16 silu; bias already in s (came through the MFMA C-operand in f32)
__device__ __forceinline__ half4 silu4nb(const f32x4& s) {
  h2v x01 = __builtin_bit_cast(h2v, __builtin_amdgcn_cvt_pkrtz(s[0], s[1]));
  h2v x23 = __builtin_bit_cast(h2v, __builtin_amdgcn_cvt_pkrtz(s[2], s[3]));
  const h2v NL2E = {(_Float16)-1.44269504f, (_Float16)-1.44269504f};
  const h2v ONE = {(_Float16)1.0f, (_Float16)1.0f};
  h2v m01 = x01 * NL2E, m23 = x23 * NL2E;
  h2v e01 = __builtin_bit_cast(h2v, h2exp2(__builtin_bit_cast(__half2, m01)));
  h2v e23 = __builtin_bit_cast(h2v, h2exp2(__builtin_bit_cast(__half2, m23)));
  h2v d01 = e01 + ONE, d23 = e23 + ONE;
  h2v y01 = x01 * __builtin_bit_cast(h2v, h2rcp(__builtin_bit_cast(__half2, d01)));
  h2v y23 = x23 * __builtin_bit_cast(h2v, h2rcp(__builtin_bit_cast(__half2, d23)));
  return (half4){y01[0], y01[1], y23[0], y23[1]};
}

struct BiasSet { f32x4 b[2][2]; };  // [qs][k2], f32 — feeds QK C-operand

// =================== main: R16 body, bpermute -> LDS pair-table gather ===================
// The 16/tile ds_bpermute bias gathers are the ONE component in every kernel since R1,
// never ablated. Replace with a 441-entry (rb[i],rb[j]) float2 LDS table (built once per
// block); per tile: 8 ds_read_b64 gathers (pair-indices packed by prepass) vs 16 bpermute
// + 16 extracts. Bias values numerically identical (f32, via QK C-operand).
__global__ __launch_bounds__(256, 4) void pa_main(
    const _Float16* __restrict__ KF, const _Float16* __restrict__ VF,
    const unsigned char* __restrict__ PB, const float* __restrict__ q,
    const float* __restrict__ relbias, float* __restrict__ out) {
  __shared__ _Float16 ldsK[2][2048];
  __shared__ _Float16 ldsV[2][2048];
  __shared__ f32x2 tabF[441];   // (rb[i], rb[j]) for pair-index i*21+j; rb[20] = -3e4

  const int tid = threadIdx.x, lane = tid & 63, wid = tid >> 6;
  const int l16 = lane & 15, g4 = lane >> 4;
  const int xcd = blockIdx.x & 7;        // bid%8 = XCD
  const int i = blockIdx.x >> 3;         // 0..63 within XCD
  const int b = xcd >> 2;                // XCD owns (b, 4-head group)
  const int hg = xcd & 3;
  const int h = hg * 4 + (i & 3);
  const int qgrp = i >> 2;               // 0..15
  const int qblk = qgrp * 4 + wid;
  const int qbase = qblk * 32;

  // build pair table (441 entries, 2 rounds of 256 threads)
  for (int e = tid; e < 441; e += 256) {
    int bi = e / 21, bj = e - bi * 21;
    float vi = (bi < NB) ? relbias[bi * NH + h] : -30000.0f;
    float vj = (bj < NB) ? relbias[bj * NH + h] : -30000.0f;
    tabF[e] = (f32x2){vi, vj};
  }

  half8 qf[2][2];
#pragma unroll
  for (int qs = 0; qs < 2; ++qs)
#pragma unroll
    for (int dh = 0; dh < 2; ++dh) {
      const float* s = q + ((size_t)(b * SEQ + qbase + qs * 16 + l16)) * DM + h * 64 + dh * 32 + g4 * 8;
      f32x4 a = *(const f32x4*)s;
      f32x4 c = *(const f32x4*)(s + 4);
      qf[qs][dh] = {(_Float16)(a[0] * 0.125f), (_Float16)(a[1] * 0.125f),
                    (_Float16)(a[2] * 0.125f), (_Float16)(a[3] * 0.125f),
                    (_Float16)(c[0] * 0.125f), (_Float16)(c[1] * 0.125f),
                    (_Float16)(c[2] * 0.125f), (_Float16)(c[3] * 0.125f)};
    }

  f32x4 acc[2][4];
#pragma unroll
  for (int qs = 0; qs < 2; ++qs)
#pragma unroll
    for (int dt = 0; dt < 4; ++dt) acc[qs][dt] = (f32x4){0.f, 0.f, 0.f, 0.f};

  const _Float16* kfb = KF + ((size_t)((b * 16 + h) * 64)) * 2048 + lane * 8;
  const _Float16* vfb = VF + ((size_t)((b * 16 + h) * 64)) * 2048 + lane * 8;
  const unsigned char* pbb = PB + ((size_t)(b * 64 + qblk)) * 65536 + lane * 16;
  const int c512 = wid * 512;

#define STAGE(T, B)                                          \
  do {                                                       \
    gll16(kfb + (size_t)(T) * 2048 + c512, &ldsK[B][c512]);  \
    gll16(vfb + (size_t)(T) * 2048 + c512, &ldsV[B][c512]);  \
  } while (0)
#define CLMP(T) ((T) < 64 ? (T) : 63)

#define GATHER(BS, PQ)                                                 \
  do {                                                                 \
    _Pragma("unroll") for (int qs = 0; qs < 2; ++qs)                   \
      _Pragma("unroll") for (int k2 = 0; k2 < 2; ++k2) {               \
        u32 w = (u32)PQ[qs * 2 + k2];                                  \
        f32x2 p01 = tabF[w & 0xffffu];                                 \
        f32x2 p23 = tabF[w >> 16];                                     \
        BS.b[qs][k2] = (f32x4){p01[0], p01[1], p23[0], p23[1]};        \
      }                                                                \
  } while (0)

#define COMPUTE(B, BS)                                                                       \
  do {                                                                                       \
    half8 kfr[4], vvr[4];                                                                    \
    _Pragma("unroll") for (int j = 0; j < 4; ++j) {                                          \
      kfr[j] = *(const half8*)&ldsK[B][j * 512 + lane * 8];                                  \
      vvr[j] = *(const half8*)&ldsV[B][j * 512 + lane * 8];                                  \
    }                                                                                        \
    f32x4 sa[2][2];                                                                          \
    _Pragma("unroll") for (int qs = 0; qs < 2; ++qs)                                         \
      _Pragma("unroll") for (int k2 = 0; k2 < 2; ++k2) {                                     \
        sa[qs][k2] = __builtin_amdgcn_mfma_f32_16x16x32_f16(kfr[k2 * 2 + 0], qf[qs][0],      \
                                                            BS.b[qs][k2], 0, 0, 0);          \
        sa[qs][k2] = __builtin_amdgcn_mfma_f32_16x16x32_f16(kfr[k2 * 2 + 1], qf[qs][1],      \
                                                            sa[qs][k2], 0, 0, 0);            \
      }                                                                                      \
    half8 pf8[2];                                                                            \
    _Pragma("unroll") for (int qs = 0; qs < 2; ++qs) {                                       \
      half4 p0 = silu4nb(sa[qs][0]);                                                         \
      half4 p1 = silu4nb(sa[qs][1]);                                                         \
      pf8[qs] = (half8){p0[0], p0[1], p0[2], p0[3], p1[0], p1[1], p1[2], p1[3]};             \
    }                                                                                        \
    _Pragma("unroll") for (int qs = 0; qs < 2; ++qs)                                         \
      _Pragma("unroll") for (int dt = 0; dt < 4; ++dt)                                       \
        acc[qs][dt] = __builtin_amdgcn_mfma_f32_16x16x32_f16(pf8[qs], vvr[dt],               \
                                                             acc[qs][dt], 0, 0, 0);          \
  } while (0)

  BiasSet biasA, biasB;
  i32x4 pq1, pqX;

  // prologue: stage tile0 -> buf0; table built; bias(0); pq(1) in flight
  STAGE(0, 0);
  i32x4 pq0 = *(const i32x4*)(pbb);
  pq1 = *(const i32x4*)(pbb + 1024);
  __syncthreads();                      // drains stage(0), publishes table
  GATHER(biasA, pq0);

  for (int t = 0; t < 64; t += 2) {
    // even phase: stage t+1 -> buf1; compute t from buf0
    STAGE(t + 1, 1);
    pqX = *(const i32x4*)(pbb + (size_t)CLMP(t + 2) * 1024);
    __builtin_amdgcn_sched_barrier(0);
    GATHER(biasB, pq1);                 // bias for t+1, hides under compute t
    COMPUTE(0, biasA);
    __syncthreads();                    // buf1 ready; all waves done with buf0
    // odd phase: stage t+2 -> buf0; compute t+1 from buf1
    STAGE(CLMP(t + 2), 0);
    pq1 = *(const i32x4*)(pbb + (size_t)CLMP(t + 3) * 1024);
    __builtin_amdgcn_sched_barrier(0);
    GATHER(biasA, pqX);                 // bias for t+2
    COMPUTE(1, biasB);
    __syncthreads();
  }
#undef STAGE
#undef CLMP
#undef GATHER
#undef COMPUTE

  // epilogue: full-k accumulators -> direct stores (no memset, no atomics)
#pragma unroll
  for (int qs = 0; qs < 2; ++qs)
#pragma unroll
    for (int dt = 0; dt < 4; ++dt)
#pragma unroll
      for (int r = 0; r < 4; ++r) {
        int qrow = qbase + qs * 16 + g4 * 4 + r;
        int d = h * 64 + dt * 16 + l16;
        out[((size_t)(b * SEQ) + qrow) * DM + d] = acc[qs][dt][r];
      }
}

extern "C" void kernel_launch(void* const* d_in, const int* in_sizes, int n_in,
                              void* d_out, int out_size, void* d_ws, size_t ws_size,
                              hipStream_t stream) {
  const float* v = (const float*)d_in[0];
  const float* k = (const float*)d_in[1];
  const float* q = (const float*)d_in[2];
  const int* mask = (const int*)d_in[3];
  const int* diff = (const int*)d_in[4];
  const float* relbias = (const float*)d_in[5];
  float* out = (float*)d_out;

  _Float16* KF = (_Float16*)d_ws;
  _Float16* VF = KF + KF_HALVES;
  unsigned char* PB = (unsigned char*)(VF + VF_HALVES);
  if (ws_size < (size_t)25165824) return;

  pa_prep<<<7168, 256, 0, stream>>>(v, k, diff, mask, KF, VF, PB);
  pa_main<<<512, 256, 0, stream>>>(KF, VF, PB, q, relbias, out);
}